// Round 15
// baseline (240.103 us; speedup 1.0000x reference)
//
#include <hip/hip_runtime.h>

typedef unsigned short u16;
typedef __bf16 bf16x8 __attribute__((ext_vector_type(8)));
typedef float f32x4 __attribute__((ext_vector_type(4)));
typedef u16   u16x8 __attribute__((ext_vector_type(8)));

__device__ __forceinline__ u16 f2bf(float f) {
  __bf16 b = (__bf16)f;
  return __builtin_bit_cast(u16, b);
}
__device__ __forceinline__ float bf2f(u16 u) {
  unsigned int x = ((unsigned int)u) << 16;
  return __builtin_bit_cast(float, x);
}

// async global->LDS, 16B per lane. LDS dest: wave-uniform base + lane*16.
__device__ __forceinline__ void gll16(const u16* g, u16* l) {
  __builtin_amdgcn_global_load_lds(
      (const __attribute__((address_space(1))) void*)g,
      (__attribute__((address_space(3))) void*)l, 16, 0, 0);
}

// ---------------- f32 -> bf16 conversion kernels ----------------------------
__global__ __launch_bounds__(256) void convw_kernel(
    const float* __restrict__ w0, const float* __restrict__ w1,
    const float* __restrict__ w2, const float* __restrict__ w3,
    u16* __restrict__ o0, u16* __restrict__ o1,
    u16* __restrict__ o2, u16* __restrict__ o3)
{
  const int z = blockIdx.z;
  const float* s = (z == 0) ? w0 : (z == 1) ? w1 : (z == 2) ? w2 : w3;
  u16* o = (z == 0) ? o0 : (z == 1) ? o1 : (z == 2) ? o2 : o3;
  const long i = ((long)blockIdx.x * 256 + threadIdx.x) * 8;
  f32x4 a = *(const f32x4*)(s + i);
  f32x4 b = *(const f32x4*)(s + i + 4);
  u16x8 r;
#pragma unroll
  for (int e = 0; e < 4; ++e) { r[e] = f2bf(a[e]); r[e + 4] = f2bf(b[e]); }
  *(u16x8*)(o + i) = r;
}

__global__ __launch_bounds__(256) void convact_kernel(
    const float* __restrict__ a0, const float* __restrict__ a1,
    const float* __restrict__ a2,
    u16* __restrict__ o0, u16* __restrict__ o1, u16* __restrict__ o2)
{
  const int z = blockIdx.z;
  const float* s = (z == 0) ? a0 : (z == 1) ? a1 : a2;
  u16* o = (z == 0) ? o0 : (z == 1) ? o1 : o2;
  const long i = ((long)blockIdx.x * 256 + threadIdx.x) * 8;
  f32x4 a = *(const f32x4*)(s + i);
  f32x4 b = *(const f32x4*)(s + i + 4);
  u16x8 r;
#pragma unroll
  for (int e = 0; e < 4; ++e) { r[e] = f2bf(a[e]); r[e + 4] = f2bf(b[e]); }
  *(u16x8*)(o + i) = r;
}

// ---------------- MFMA GEMM: 256x256 tile, 8 waves, 2-deep pipeline ---------
// C[m,n] = sum_k A[m,k]*W[n,k] + bias[n]. A: [rows][1024] bf16.
// Bw: [1024][1024] bf16 (row n = output col n). BK=64, 16 K-steps.
// Traffic-minimizing tile: per-z operand traffic = 8.4MB*4 + 2.1MB*16 ~ 68MB
// (vs ~200MB at 64x128). 8 waves (2M x 4N), wave tile 128x64, acc[8][4].
// LDS 128KB dbuf; r13-green swizzle (pre-swizzled source col, XOR read);
// counted vmcnt(8) waits (tile t's 8 loads; t+1's stay in flight).
template<int OUT_F32>
__global__ __launch_bounds__(512, 2) void gemm256(
    const u16* __restrict__ A0, const u16* __restrict__ A1, const u16* __restrict__ A2,
    const u16* __restrict__ B0, const u16* __restrict__ B1, const u16* __restrict__ B2,
    const float* __restrict__ g0, const float* __restrict__ g1, const float* __restrict__ g2,
    void* __restrict__ C0, void* __restrict__ C1, void* __restrict__ C2, int Mvalid)
{
  const int z = blockIdx.z;
  const u16* Ab = (z == 0) ? A0 : (z == 1) ? A1 : A2;
  const u16* Bw = (z == 0) ? B0 : (z == 1) ? B1 : B2;
  const float* bias = (z == 0) ? g0 : (z == 1) ? g1 : g2;
  void* Cout = (z == 0) ? C0 : (z == 1) ? C1 : C2;

  __shared__ __align__(16) u16 As[2][256 * 64];   // 32KB per buffer
  __shared__ __align__(16) u16 Bs[2][256 * 64];   // total LDS 128KB

  const int tid = threadIdx.x;
  const int wid = tid >> 6, lane = tid & 63, ln = lane & 15, lg = lane >> 4;
  const int row0 = blockIdx.x * 256, col0 = blockIdx.y * 256;
  const int wrow = (wid >> 2) * 128, wcol = (wid & 3) * 64;
  const int lr8 = lane >> 3;                       // row within 8-row group
  const int kslot = 8 * ((lane & 7) ^ lr8);        // pre-swizzled source k-offset

  auto stage = [&](int buf, int kt) {
    const int k0 = kt * 64;
#pragma unroll
    for (int c = 0; c < 4; ++c) {                  // A: 4 wave-loads (8 rows each)
      int base = wid * 32 + c * 8;
      long gr = row0 + base + lr8; if (gr >= Mvalid) gr = Mvalid - 1;
      gll16(Ab + gr * 1024 + k0 + kslot, &As[buf][base * 64]);
    }
#pragma unroll
    for (int c = 0; c < 4; ++c) {                  // B: 4 wave-loads
      int base = wid * 32 + c * 8;
      gll16(Bw + (long)(col0 + base + lr8) * 1024 + k0 + kslot, &Bs[buf][base * 64]);
    }
  };

  f32x4 acc[8][4] = {};
  stage(0, 0);
  stage(1, 1);                                     // 16 loads in flight per wave

  for (int kt = 0; kt < 16; ++kt) {
    const int buf = kt & 1;
    if (kt < 15) asm volatile("s_waitcnt vmcnt(8)" ::: "memory");
    else         asm volatile("s_waitcnt vmcnt(0)" ::: "memory");
    __builtin_amdgcn_sched_barrier(0);
    __builtin_amdgcn_s_barrier();                  // tile kt staged for all waves

#pragma unroll
    for (int kk = 0; kk < 64; kk += 32) {
      bf16x8 af[8], bfr[4];
#pragma unroll
      for (int i = 0; i < 8; ++i) {
        int r = wrow + i * 16 + ln;
        af[i] = *(const bf16x8*)&As[buf][r * 64 + ((kk + 8 * lg) ^ ((r & 7) << 3))];
      }
#pragma unroll
      for (int j = 0; j < 4; ++j) {
        int r = wcol + j * 16 + ln;
        bfr[j] = *(const bf16x8*)&Bs[buf][r * 64 + ((kk + 8 * lg) ^ ((r & 7) << 3))];
      }
#pragma unroll
      for (int i = 0; i < 8; ++i)
#pragma unroll
        for (int j = 0; j < 4; ++j)
          acc[i][j] = __builtin_amdgcn_mfma_f32_16x16x32_bf16(af[i], bfr[j], acc[i][j], 0, 0, 0);
    }

    __builtin_amdgcn_s_barrier();                  // all waves done reading buf
    if (kt + 2 < 16) stage(buf, kt + 2);           // refill freed buffer
  }

  float bj[4];
#pragma unroll
  for (int j = 0; j < 4; ++j) bj[j] = bias[col0 + wcol + j * 16 + ln];
#pragma unroll
  for (int i = 0; i < 8; ++i)
#pragma unroll
    for (int j = 0; j < 4; ++j)
#pragma unroll
      for (int reg = 0; reg < 4; ++reg) {
        int r = row0 + wrow + i * 16 + 4 * lg + reg;
        int c = col0 + wcol + j * 16 + ln;
        if (r < Mvalid) {
          float v = acc[i][j][reg] + bj[j];
          if constexpr (OUT_F32) ((float*)Cout)[(long)r * 1024 + c] = v;
          else                   ((u16*)Cout)[(long)r * 1024 + c] = f2bf(v);
        }
      }
}

// ---------------- MFMA flash attention (unchanged, green since round 9) -----
__global__ __launch_bounds__(256) void MaskedMultiheadAttention_51591147160164_kernel(
    const u16* __restrict__ Qb, const u16* __restrict__ Kb,
    const u16* __restrict__ Vb, const int* __restrict__ maskp,
    float* __restrict__ Aout, u16* __restrict__ ctx)
{
  __shared__ __align__(16) u16 Qs[64 * 72];
  __shared__ __align__(16) u16 Ks[32 * 72];
  __shared__ __align__(16) u16 Vs[64 * 40];
  __shared__ __align__(16) u16 Ps[4][16 * 40];

  const int qb = 15 - blockIdx.x;
  const int bh = blockIdx.y;
  const int b = bh >> 4, h = bh & 15;
  const int q0 = qb * 64;
  const int tid = threadIdx.x;
  const int wid = tid >> 6, lane = tid & 63, ln = lane & 15, lg = lane >> 4;
  const int nkt = 2 * qb + 2;

#pragma unroll
  for (int p = 0; p < 2; ++p) {
    int idx = p * 256 + tid;
    int r = idx >> 3, u = idx & 7;
    int tok = q0 + r; if (tok > 999) tok = 999;
    *(u16x8*)&Qs[r * 72 + u * 8] =
        *(const u16x8*)(Qb + (long)(b * 1000 + tok) * 1024 + h * 64 + u * 8);
  }
  __syncthreads();

  bf16x8 qf0, qf1;
  {
    int r = wid * 16 + ln;
    qf0 = *(const bf16x8*)&Qs[r * 72 +      8 * lg];
    qf1 = *(const bf16x8*)&Qs[r * 72 + 32 + 8 * lg];
  }

  const int kr = tid >> 3, ku = tid & 7;
  const int qrow = q0 + wid * 16 + 4 * lg;

  auto computeS = [&](f32x4 sf[2]) {
#pragma unroll
    for (int j = 0; j < 2; ++j) {
      int kk = j * 16 + ln;
      bf16x8 kf0 = *(const bf16x8*)&Ks[kk * 72 +      8 * lg];
      bf16x8 kf1 = *(const bf16x8*)&Ks[kk * 72 + 32 + 8 * lg];
      f32x4 zz = {0.f, 0.f, 0.f, 0.f};
      zz = __builtin_amdgcn_mfma_f32_16x16x32_bf16(qf0, kf0, zz, 0, 0, 0);
      zz = __builtin_amdgcn_mfma_f32_16x16x32_bf16(qf1, kf1, zz, 0, 0, 0);
      sf[j] = zz;
    }
  };

  float m[4], l[4];
#pragma unroll
  for (int i = 0; i < 4; ++i) { m[i] = -3.0e38f; l[i] = 0.f; }

  for (int kt = 0; kt < nkt; ++kt) {
    int tok = kt * 32 + kr; if (tok > 999) tok = 999;
    u16x8 w = *(const u16x8*)(Kb + (long)(b * 1000 + tok) * 1024 + h * 64 + ku * 8);
    __syncthreads();
    *(u16x8*)&Ks[kr * 72 + ku * 8] = w;
    __syncthreads();

    f32x4 sf[2]; computeS(sf);
    int ki0 = kt * 32 + ln, ki1 = ki0 + 16;
    int mv0 = (ki0 < 1000) ? maskp[b * 1000 + ki0] : 0;
    int mv1 = (ki1 < 1000) ? maskp[b * 1000 + ki1] : 0;
#pragma unroll
    for (int reg = 0; reg < 4; ++reg) {
      int qi = qrow + reg;
      float s0 = (mv0 && ki0 <= qi) ? sf[0][reg] * 0.125f : -1.0e30f;
      float s1 = (mv1 && ki1 <= qi) ? sf[1][reg] * 0.125f : -1.0e30f;
      float mx = fmaxf(s0, s1);
#pragma unroll
      for (int d = 1; d < 16; d <<= 1) mx = fmaxf(mx, __shfl_xor(mx, d));
      float mnew = fmaxf(m[reg], mx);
      float sum = __expf(s0 - mnew) + __expf(s1 - mnew);
#pragma unroll
      for (int d = 1; d < 16; d <<= 1) sum += __shfl_xor(sum, d);
      l[reg] = l[reg] * __expf(m[reg] - mnew) + sum;
      m[reg] = mnew;
    }
  }

  float rl[4];
#pragma unroll
  for (int i = 0; i < 4; ++i) rl[i] = 1.0f / l[i];

  f32x4 cacc[4] = {};

  for (int kt = 0; kt < nkt; ++kt) {
    int tok = kt * 32 + kr; if (tok > 999) tok = 999;
    u16x8 w = *(const u16x8*)(Kb + (long)(b * 1000 + tok) * 1024 + h * 64 + ku * 8);
    u16x8 v8 = *(const u16x8*)(Vb + (long)(b * 1000 + tok) * 1024 + h * 64 + ku * 8);
    __syncthreads();
    *(u16x8*)&Ks[kr * 72 + ku * 8] = w;
#pragma unroll
    for (int e = 0; e < 8; ++e)
      Vs[(ku * 8 + e) * 40 + kr] = v8[e];
    __syncthreads();

    f32x4 sf[2]; computeS(sf);
#pragma unroll
    for (int j = 0; j < 2; ++j) {
      int ki = kt * 32 + j * 16 + ln;
      int mv = (ki < 1000) ? maskp[b * 1000 + ki] : 0;
#pragma unroll
      for (int reg = 0; reg < 4; ++reg) {
        int qi = qrow + reg;
        float p = (mv && ki <= qi) ? __expf(sf[j][reg] * 0.125f - m[reg]) * rl[reg] : 0.f;
        if (qi < 1000 && ki < 1000)
          Aout[((long)bh * 1000 + qi) * 1000 + ki] = p;
        Ps[wid][(4 * lg + reg) * 40 + j * 16 + ln] = f2bf(p);
      }
    }
    __syncthreads();
    bf16x8 pf = *(const bf16x8*)&Ps[wid][ln * 40 + 8 * lg];
#pragma unroll
    for (int jn = 0; jn < 4; ++jn) {
      bf16x8 vf = *(const bf16x8*)&Vs[(jn * 16 + ln) * 40 + 8 * lg];
      cacc[jn] = __builtin_amdgcn_mfma_f32_16x16x32_bf16(pf, vf, cacc[jn], 0, 0, 0);
    }
  }

#pragma unroll
  for (int jn = 0; jn < 4; ++jn)
#pragma unroll
    for (int reg = 0; reg < 4; ++reg) {
      int qi = qrow + reg;
      if (qi < 1000)
        ctx[(long)(b * 1000 + qi) * 1024 + h * 64 + jn * 16 + ln] = f2bf(cacc[jn][reg]);
    }
}

// ---------------- launch ----------------------------------------------------
extern "C" void kernel_launch(void* const* d_in, const int* in_sizes, int n_in,
                              void* d_out, int out_size, void* d_ws, size_t ws_size,
                              hipStream_t stream)
{
  const float* q  = (const float*)d_in[0];
  const float* k  = (const float*)d_in[1];
  const float* v  = (const float*)d_in[2];
  const int*  msk = (const int*)d_in[3];
  const float* Wq = (const float*)d_in[4];
  const float* bq = (const float*)d_in[5];
  const float* Wk = (const float*)d_in[6];
  const float* bk = (const float*)d_in[7];
  const float* Wv = (const float*)d_in[8];
  const float* bv = (const float*)d_in[9];
  const float* Wp = (const float*)d_in[10];
  const float* bp = (const float*)d_in[11];

  u16* ws  = (u16*)d_ws;                     // 56 MB total
  u16* Qc  = ws;                             // [4000][1024] bf16 (q cast; ctx aliases later)
  u16* Kc  = ws + 4096000u;                  // [4000][1024] bf16 (k cast)
  u16* Vc  = ws + 2u * 4096000u;             // [4000][1024] bf16 (v cast)
  u16* Qb  = ws + 3u * 4096000u;             // [4000][1024] bf16 (Q proj)
  u16* Kb  = ws + 4u * 4096000u;             // [4000][1024] bf16 (K proj)
  u16* Vb  = ws + 5u * 4096000u;             // [4000][1024] bf16 (V proj)
  u16* wqb = ws + 6u * 4096000u;             // [1024][1024] bf16
  u16* wkb = wqb + (1u << 20);
  u16* wvb = wkb + (1u << 20);
  u16* wpb = wvb + (1u << 20);
  u16* ctx = Qc;                             // alias: Qc dead after QKV GEMM

  float* Xout = (float*)d_out;               // [4000][1024] f32 (output x)
  float* Aout = Xout + 4096000;              // [64][1000][1000] f32 (output A)

  convw_kernel<<<dim3(512, 1, 4), 256, 0, stream>>>(Wq, Wk, Wv, Wp, wqb, wkb, wvb, wpb);
  convact_kernel<<<dim3(2000, 1, 3), 256, 0, stream>>>(q, k, v, Qc, Kc, Vc);
  // fused QKV projections: 256x256 tiles, grid (16,4,3)=192 blocks
  gemm256<0><<<dim3(16, 4, 3), 512, 0, stream>>>(
      Qc, Kc, Vc, wqb, wkb, wvb, bq, bk, bv, Qb, Kb, Vb, 4000);
  MaskedMultiheadAttention_51591147160164_kernel<<<dim3(16, 64), 256, 0, stream>>>(
      Qb, Kb, Vb, msk, Aout, ctx);
  // output projection: 256x256 tiles, grid (16,4)=64 blocks
  gemm256<1><<<dim3(16, 4, 1), 512, 0, stream>>>(
      ctx, ctx, ctx, wpb, wpb, wpb, bp, bp, bp, Xout, Xout, Xout, 4000);
}

// Round 16
// 180.705 us; speedup vs baseline: 1.3287x; 1.3287x over previous
//
#include <hip/hip_runtime.h>

typedef unsigned short u16;
typedef __bf16 bf16x8 __attribute__((ext_vector_type(8)));
typedef float f32x4 __attribute__((ext_vector_type(4)));
typedef u16   u16x8 __attribute__((ext_vector_type(8)));

__device__ __forceinline__ u16 f2bf(float f) {
  __bf16 b = (__bf16)f;
  return __builtin_bit_cast(u16, b);
}
__device__ __forceinline__ float bf2f(u16 u) {
  unsigned int x = ((unsigned int)u) << 16;
  return __builtin_bit_cast(float, x);
}

// async global->LDS, 16B per lane. LDS dest: wave-uniform base + lane*16.
__device__ __forceinline__ void gll16(const u16* g, u16* l) {
  __builtin_amdgcn_global_load_lds(
      (const __attribute__((address_space(1))) void*)g,
      (__attribute__((address_space(3))) void*)l, 16, 0, 0);
}

// ---------------- f32 -> bf16 conversion kernels ----------------------------
__global__ __launch_bounds__(256) void convw_kernel(
    const float* __restrict__ w0, const float* __restrict__ w1,
    const float* __restrict__ w2, const float* __restrict__ w3,
    u16* __restrict__ o0, u16* __restrict__ o1,
    u16* __restrict__ o2, u16* __restrict__ o3)
{
  const int z = blockIdx.z;
  const float* s = (z == 0) ? w0 : (z == 1) ? w1 : (z == 2) ? w2 : w3;
  u16* o = (z == 0) ? o0 : (z == 1) ? o1 : (z == 2) ? o2 : o3;
  const long i = ((long)blockIdx.x * 256 + threadIdx.x) * 8;
  f32x4 a = *(const f32x4*)(s + i);
  f32x4 b = *(const f32x4*)(s + i + 4);
  u16x8 r;
#pragma unroll
  for (int e = 0; e < 4; ++e) { r[e] = f2bf(a[e]); r[e + 4] = f2bf(b[e]); }
  *(u16x8*)(o + i) = r;
}

__global__ __launch_bounds__(256) void convact_kernel(
    const float* __restrict__ a0, const float* __restrict__ a1,
    const float* __restrict__ a2,
    u16* __restrict__ o0, u16* __restrict__ o1, u16* __restrict__ o2)
{
  const int z = blockIdx.z;
  const float* s = (z == 0) ? a0 : (z == 1) ? a1 : a2;
  u16* o = (z == 0) ? o0 : (z == 1) ? o1 : o2;
  const long i = ((long)blockIdx.x * 256 + threadIdx.x) * 8;
  f32x4 a = *(const f32x4*)(s + i);
  f32x4 b = *(const f32x4*)(s + i + 4);
  u16x8 r;
#pragma unroll
  for (int e = 0; e < 4; ++e) { r[e] = f2bf(a[e]); r[e + 4] = f2bf(b[e]); }
  *(u16x8*)(o + i) = r;
}

// ---------------- MFMA GEMM (r13 config — fastest measured) -----------------
// C[m,n] = sum_k A[m,k]*W[n,k] + bias[n]. BM x 128 tile, BK=64, 16 K-steps.
// Linear LDS dest + pre-swizzled source col; read offset (kk+8lg)^((r&7)<<3).
template<int BM, int OUT_F32>
__global__ __launch_bounds__(256, 3) void gemm_swz(
    const u16* __restrict__ A0, const u16* __restrict__ A1, const u16* __restrict__ A2,
    const u16* __restrict__ B0, const u16* __restrict__ B1, const u16* __restrict__ B2,
    const float* __restrict__ g0, const float* __restrict__ g1, const float* __restrict__ g2,
    void* __restrict__ C0, void* __restrict__ C1, void* __restrict__ C2, int Mvalid)
{
  constexpr int ACH = BM / 32;
  constexpr int MI  = BM / 32;
  const int z = blockIdx.z;
  const u16* Ab = (z == 0) ? A0 : (z == 1) ? A1 : A2;
  const u16* Bw = (z == 0) ? B0 : (z == 1) ? B1 : B2;
  const float* bias = (z == 0) ? g0 : (z == 1) ? g1 : g2;
  void* Cout = (z == 0) ? C0 : (z == 1) ? C1 : C2;

  __shared__ __align__(16) u16 As[BM * 64];
  __shared__ __align__(16) u16 Bs[128 * 64];

  const int tid = threadIdx.x;
  const int wid = tid >> 6, lane = tid & 63, ln = lane & 15, lg = lane >> 4;
  const int row0 = blockIdx.x * BM, col0 = blockIdx.y * 128;
  const int wr = (wid >> 1) * (BM / 2), wc = (wid & 1) * 64;
  const int lr8 = lane >> 3;
  const int kslot = 8 * ((lane & 7) ^ lr8);

  f32x4 acc[MI][4] = {};

  for (int kt = 0; kt < 16; ++kt) {
    const int k0 = kt * 64;
    __syncthreads();
#pragma unroll
    for (int c = 0; c < ACH; ++c) {
      int base = wid * (8 * ACH) + c * 8;
      long gr = row0 + base + lr8; if (gr >= Mvalid) gr = Mvalid - 1;
      gll16(Ab + gr * 1024 + k0 + kslot, &As[base * 64]);
    }
#pragma unroll
    for (int c = 0; c < 4; ++c) {
      int base = wid * 32 + c * 8;
      gll16(Bw + (long)(col0 + base + lr8) * 1024 + k0 + kslot, &Bs[base * 64]);
    }
    __syncthreads();

#pragma unroll
    for (int kk = 0; kk < 64; kk += 32) {
      bf16x8 af[MI], bfr[4];
#pragma unroll
      for (int i = 0; i < MI; ++i) {
        int r = wr + i * 16 + ln;
        af[i] = *(const bf16x8*)&As[r * 64 + ((kk + 8 * lg) ^ ((r & 7) << 3))];
      }
#pragma unroll
      for (int j = 0; j < 4; ++j) {
        int r = wc + j * 16 + ln;
        bfr[j] = *(const bf16x8*)&Bs[r * 64 + ((kk + 8 * lg) ^ ((r & 7) << 3))];
      }
#pragma unroll
      for (int i = 0; i < MI; ++i)
#pragma unroll
        for (int j = 0; j < 4; ++j)
          acc[i][j] = __builtin_amdgcn_mfma_f32_16x16x32_bf16(af[i], bfr[j], acc[i][j], 0, 0, 0);
    }
  }

  float bj[4];
#pragma unroll
  for (int j = 0; j < 4; ++j) bj[j] = bias[col0 + wc + j * 16 + ln];
#pragma unroll
  for (int i = 0; i < MI; ++i)
#pragma unroll
    for (int j = 0; j < 4; ++j)
#pragma unroll
      for (int reg = 0; reg < 4; ++reg) {
        int r = row0 + wr + i * 16 + 4 * lg + reg;
        int c = col0 + wc + j * 16 + ln;
        if (r < Mvalid) {
          float v = acc[i][j][reg] + bj[j];
          if constexpr (OUT_F32) ((float*)Cout)[(long)r * 1024 + c] = v;
          else                   ((u16*)Cout)[(long)r * 1024 + c] = f2bf(v);
        }
      }
}

// ---------------- MFMA flash attention v2: KVBLK=64, pipelined staging ------
// grid (16 qblocks reversed, 64 b*h), 4 waves; wave = 16 q-rows.
// K: 2-deep gll dbuf + counted vmcnt; V: reg-staged 2-deep (parity sets),
// write-late into single Vs; mask in LDS; K swizzled (pre-swizzled source).
__global__ __launch_bounds__(256) void MaskedMultiheadAttention_51591147160164_kernel(
    const u16* __restrict__ Qb, const u16* __restrict__ Kb,
    const u16* __restrict__ Vb, const int* __restrict__ maskp,
    float* __restrict__ Aout, u16* __restrict__ ctx)
{
  __shared__ __align__(16) u16 QsPs[64 * 72];   // Qs (prologue) then Ps (pass 2)
  __shared__ __align__(16) u16 Ks[2][64 * 64];
  __shared__ __align__(16) u16 Vs[64 * 72];     // V^T tile [d=64][key=64]+pad
  __shared__ int Ms[1000];

  const int qb = 15 - blockIdx.x;
  const int bh = blockIdx.y;
  const int b = bh >> 4, h = bh & 15;
  const int q0 = qb * 64;
  const int tid = threadIdx.x;
  const int wid = tid >> 6, lane = tid & 63, ln = lane & 15, lg = lane >> 4;
  const int nkt = qb + 1;                       // 64-wide k-tiles

  // ---- stage Q (64x64) + mask ----
#pragma unroll
  for (int p = 0; p < 2; ++p) {
    int idx = p * 256 + tid;
    int r = idx >> 3, u = idx & 7;
    int tok = q0 + r; if (tok > 999) tok = 999;
    *(u16x8*)&QsPs[r * 72 + u * 8] =
        *(const u16x8*)(Qb + (long)(b * 1000 + tok) * 1024 + h * 64 + u * 8);
  }
  if (tid < 250)
    *(int4*)&Ms[tid * 4] = *(const int4*)(maskp + b * 1000 + tid * 4);
  __syncthreads();

  bf16x8 qf0, qf1;
  {
    int r = wid * 16 + ln;
    qf0 = *(const bf16x8*)&QsPs[r * 72 +      8 * lg];
    qf1 = *(const bf16x8*)&QsPs[r * 72 + 32 + 8 * lg];
  }
  __syncthreads();                              // Q consumed before Ps reuse

  const int lr8 = lane >> 3;
  const int kslot = 8 * ((lane & 7) ^ lr8);     // pre-swizzled source offset
  const long rowb = (long)b * 1000;
  const int qrow = q0 + wid * 16 + 4 * lg;

  auto stageK = [&](int buf, int kt) {
#pragma unroll
    for (int c = 0; c < 2; ++c) {
      int r = wid * 16 + c * 8;
      gll16(Kb + (rowb + kt * 64 + r + lr8) * 1024 + h * 64 + kslot, &Ks[buf][r * 64]);
    }
  };
  const int vr = tid >> 2, vseg = tid & 3;      // V: 64 rows x 4 segs(16 u16)
  auto loadV = [&](int kt, u16x8& ra, u16x8& rb) {
    const u16* s = Vb + (rowb + kt * 64 + vr) * 1024 + h * 64 + vseg * 16;
    ra = *(const u16x8*)s; rb = *(const u16x8*)(s + 8);
  };
  auto writeV = [&](const u16x8& ra, const u16x8& rb) {
#pragma unroll
    for (int e = 0; e < 8; ++e) Vs[(vseg * 16 + e) * 72 + vr] = ra[e];
#pragma unroll
    for (int e = 0; e < 8; ++e) Vs[(vseg * 16 + 8 + e) * 72 + vr] = rb[e];
  };
  auto computeS = [&](int buf, f32x4 sf[4]) {
#pragma unroll
    for (int j = 0; j < 4; ++j) {
      int r = j * 16 + ln;
      int sw = (r & 7) << 3;
      bf16x8 kf0 = *(const bf16x8*)&Ks[buf][r * 64 + ((     8 * lg) ^ sw)];
      bf16x8 kf1 = *(const bf16x8*)&Ks[buf][r * 64 + ((32 + 8 * lg) ^ sw)];
      f32x4 z = {0.f, 0.f, 0.f, 0.f};
      z = __builtin_amdgcn_mfma_f32_16x16x32_bf16(qf0, kf0, z, 0, 0, 0);
      z = __builtin_amdgcn_mfma_f32_16x16x32_bf16(qf1, kf1, z, 0, 0, 0);
      sf[j] = z;
    }
  };

  float m[4], l[4];
#pragma unroll
  for (int i = 0; i < 4; ++i) { m[i] = -3.0e38f; l[i] = 0.f; }

  // ---------- pass 1: row max + denom (K only) ----------
  stageK(0, 0); stageK(1, 1);
  for (int t = 0; t < nkt; ++t) {
    const int buf = t & 1;
    if (t == 0 || t + 1 < nkt) asm volatile("s_waitcnt vmcnt(2)" ::: "memory");
    else                       asm volatile("s_waitcnt vmcnt(0)" ::: "memory");
    __builtin_amdgcn_sched_barrier(0);
    __builtin_amdgcn_s_barrier();               // tile t visible to all waves

    f32x4 sf[4]; computeS(buf, sf);
#pragma unroll
    for (int reg = 0; reg < 4; ++reg) {
      int qi = qrow + reg;
      float s[4];
#pragma unroll
      for (int j = 0; j < 4; ++j) {
        int ki = t * 64 + j * 16 + ln;
        int mv = (ki <= qi) ? Ms[ki] : 0;       // ki<=qi<=999 bounds Ms
        s[j] = mv ? sf[j][reg] * 0.125f : -1.0e30f;
      }
      float mx = fmaxf(fmaxf(s[0], s[1]), fmaxf(s[2], s[3]));
#pragma unroll
      for (int d = 1; d < 16; d <<= 1) mx = fmaxf(mx, __shfl_xor(mx, d));
      float mnew = fmaxf(m[reg], mx);
      float sum = __expf(s[0] - mnew) + __expf(s[1] - mnew) +
                  __expf(s[2] - mnew) + __expf(s[3] - mnew);
#pragma unroll
      for (int d = 1; d < 16; d <<= 1) sum += __shfl_xor(sum, d);
      l[reg] = l[reg] * __expf(m[reg] - mnew) + sum;
      m[reg] = mnew;
    }
    __builtin_amdgcn_s_barrier();               // reads done before restage
    if (t + 2 < nkt) stageK(buf, t + 2);
  }

  float rl[4];
#pragma unroll
  for (int i = 0; i < 4; ++i) rl[i] = 1.0f / l[i];

  // ---------- pass 2: normalized A + PV ----------
  f32x4 cacc[4] = {};
  u16* Pw = &QsPs[wid * 16 * 72];               // per-wave P tile [16][72]

  u16x8 va0, va1, vb0, vb1;
  stageK(0, 0); loadV(0, va0, va1);
  stageK(1, 1); loadV(1, vb0, vb1);
  for (int t = 0; t < nkt; ++t) {
    const int buf = t & 1;
    if (t == 0 || t + 1 < nkt) asm volatile("s_waitcnt vmcnt(4)" ::: "memory");
    else                       asm volatile("s_waitcnt vmcnt(0)" ::: "memory");
    __builtin_amdgcn_sched_barrier(0);
    if (t & 1) writeV(vb0, vb1); else writeV(va0, va1);
    asm volatile("s_waitcnt lgkmcnt(0)" ::: "memory");
    __builtin_amdgcn_sched_barrier(0);
    __builtin_amdgcn_s_barrier();               // K(t) + V(t) staged for all

    f32x4 sf[4]; computeS(buf, sf);
#pragma unroll
    for (int j = 0; j < 4; ++j) {
      int ki = t * 64 + j * 16 + ln;
      int mv = (ki < 1000) ? Ms[ki] : 0;
#pragma unroll
      for (int reg = 0; reg < 4; ++reg) {
        int qi = qrow + reg;
        float p = (mv && ki <= qi) ? __expf(sf[j][reg] * 0.125f - m[reg]) * rl[reg] : 0.f;
        if (qi < 1000 && ki < 1000)
          Aout[((long)bh * 1000 + qi) * 1000 + ki] = p;
        Pw[(4 * lg + reg) * 72 + j * 16 + ln] = f2bf(p);
      }
    }
    asm volatile("s_waitcnt lgkmcnt(0)" ::: "memory");  // Ps same-wave RAW
    __builtin_amdgcn_sched_barrier(0);
#pragma unroll
    for (int kk = 0; kk < 64; kk += 32) {
      bf16x8 pf = *(const bf16x8*)&Pw[ln * 72 + kk + 8 * lg];
#pragma unroll
      for (int jn = 0; jn < 4; ++jn) {
        bf16x8 vf = *(const bf16x8*)&Vs[(jn * 16 + ln) * 72 + kk + 8 * lg];
        cacc[jn] = __builtin_amdgcn_mfma_f32_16x16x32_bf16(pf, vf, cacc[jn], 0, 0, 0);
      }
    }
    __builtin_amdgcn_s_barrier();               // Ks/Vs reads done
    if (t + 2 < nkt) {
      stageK(buf, t + 2);
      if (t & 1) loadV(t + 2, vb0, vb1); else loadV(t + 2, va0, va1);
    }
  }
  asm volatile("s_waitcnt vmcnt(0)" ::: "memory");  // drain prologue overstage

#pragma unroll
  for (int jn = 0; jn < 4; ++jn)
#pragma unroll
    for (int reg = 0; reg < 4; ++reg) {
      int qi = qrow + reg;
      if (qi < 1000)
        ctx[(long)(b * 1000 + qi) * 1024 + h * 64 + jn * 16 + ln] = f2bf(cacc[jn][reg]);
    }
}

// ---------------- launch ----------------------------------------------------
extern "C" void kernel_launch(void* const* d_in, const int* in_sizes, int n_in,
                              void* d_out, int out_size, void* d_ws, size_t ws_size,
                              hipStream_t stream)
{
  const float* q  = (const float*)d_in[0];
  const float* k  = (const float*)d_in[1];
  const float* v  = (const float*)d_in[2];
  const int*  msk = (const int*)d_in[3];
  const float* Wq = (const float*)d_in[4];
  const float* bq = (const float*)d_in[5];
  const float* Wk = (const float*)d_in[6];
  const float* bk = (const float*)d_in[7];
  const float* Wv = (const float*)d_in[8];
  const float* bv = (const float*)d_in[9];
  const float* Wp = (const float*)d_in[10];
  const float* bp = (const float*)d_in[11];

  u16* ws  = (u16*)d_ws;                     // 56 MB total
  u16* Qc  = ws;                             // [4000][1024] bf16 (ctx aliases later)
  u16* Kc  = ws + 4096000u;
  u16* Vc  = ws + 2u * 4096000u;
  u16* Qb  = ws + 3u * 4096000u;
  u16* Kb  = ws + 4u * 4096000u;
  u16* Vb  = ws + 5u * 4096000u;
  u16* wqb = ws + 6u * 4096000u;
  u16* wkb = wqb + (1u << 20);
  u16* wvb = wkb + (1u << 20);
  u16* wpb = wvb + (1u << 20);
  u16* ctx = Qc;

  float* Xout = (float*)d_out;               // [4000][1024] f32 (output x)
  float* Aout = Xout + 4096000;              // [64][1000][1000] f32 (output A)

  convw_kernel<<<dim3(512, 1, 4), 256, 0, stream>>>(Wq, Wk, Wv, Wp, wqb, wkb, wvb, wpb);
  convact_kernel<<<dim3(2000, 1, 3), 256, 0, stream>>>(q, k, v, Qc, Kc, Vc);
  gemm_swz<128, 0><<<dim3(32, 8, 3), 256, 0, stream>>>(
      Qc, Kc, Vc, wqb, wkb, wvb, bq, bk, bv, Qb, Kb, Vb, 4000);
  MaskedMultiheadAttention_51591147160164_kernel<<<dim3(16, 64), 256, 0, stream>>>(
      Qb, Kb, Vb, msk, Aout, ctx);
  gemm_swz<64, 1><<<dim3(63, 8, 1), 256, 0, stream>>>(
      ctx, ctx, ctx, wpb, wpb, wpb, bp, bp, bp, Xout, Xout, Xout, 4000);
}